// Round 5
// baseline (225.425 us; speedup 1.0000x reference)
//
#include <hip/hip_runtime.h>
#include <math.h>

#define SPB 3136      // spatial positions per batch (56*56)
#define NB 8
#define MTOT (NB*SPB) // 25088 = 392*64, flattened M across batch
#define EPS 1e-5f

typedef unsigned short u16;
typedef __attribute__((ext_vector_type(8))) short short8;
typedef __attribute__((ext_vector_type(4))) float float4v;

__device__ __forceinline__ float b2f(u16 v){ unsigned u=((unsigned)v)<<16; float f; __builtin_memcpy(&f,&u,4); return f; }
__device__ __forceinline__ u16 f2b(float f){ unsigned u; __builtin_memcpy(&u,&f,4); u += 0x7fffu + ((u>>16)&1u); return (u16)(u>>16); }
__device__ __forceinline__ float gelu_f(float z){ return 0.5f*z*(1.0f+erff(z*0.70710678118654752f)); }

// pack weight W[o][k] (row-major) into MFMA fragment order:
// frag chunk for (nb, ks, in) is 64 lanes x 8 bf16 contiguous;
// element (o,k): lane = ((k>>3)&3)*16 + (o&15), j = k&7
template<int K>
__device__ __forceinline__ void packw(const float* __restrict__ w, u16* __restrict__ wp, int i){
  int o = i >> (K==256 ? 8 : 9);
  int k = i & (K-1);
  int lane = ((k>>3)&3)*16 + (o&15);
  int dst = ((((o>>6)*(K/32) + (k>>5))*4 + ((o>>4)&3))*64 + lane)*8 + (k&7);
  wp[dst] = f2b(w[i]);
}

// ---- fused: fold BN constants (block 0) + cast+pack all weights to bf16 ----
// cst layout: s1[256] t1[256] sg[512] tg[512] s2[256] t2[256]
__global__ void prep_k(const float* b1,const float* g1,const float* be1,const float* m1,const float* v1,
                       const float* bg,const float* gg,const float* beg,const float* mg,const float* vg,
                       const float* b2,const float* g2,const float* be2,const float* m2,const float* v2,
                       const float* __restrict__ w1,const float* __restrict__ wg,const float* __restrict__ w2,
                       u16* __restrict__ w1p,u16* __restrict__ wgp,u16* __restrict__ w2p,
                       float* cst){
  int i = blockIdx.x*512 + threadIdx.x;
  if (blockIdx.x == 0) {
    int t = threadIdx.x;
    if (t < 256) {
      float s = g1[t]*rsqrtf(v1[t]+EPS);
      cst[t] = s; cst[256+t] = b1[t]*s + be1[t] - m1[t]*s;
      float s2 = g2[t]*rsqrtf(v2[t]+EPS);
      cst[1536+t] = s2; cst[1792+t] = b2[t]*s2 + be2[t] - m2[t]*s2;
    }
    float s = gg[t]*rsqrtf(vg[t]+EPS);
    cst[512+t] = s; cst[1024+t] = bg[t]*s + beg[t] - mg[t]*s;
  }
  if (i < 65536)  packw<256>(w1, w1p, i);
  if (i < 131072) packw<512>(w2, w2p, i);
  if (i < 262144) packw<512>(wg, wgp, i);
}

// x [b][c][s] fp32 -> xt [b][s][c] bf16
__global__ void transpose_x_k(const float* __restrict__ x, u16* __restrict__ xt){
  __shared__ float t[32][33];
  int b = blockIdx.z, ct = blockIdx.y, st = blockIdx.x;
  int ts = threadIdx.x, tc = threadIdx.y;
  #pragma unroll
  for (int i=0;i<4;i++){
    int c = tc + i*8;
    t[c][ts] = x[((size_t)(b*256 + ct*32 + c))*SPB + st*32 + ts];
  }
  __syncthreads();
  #pragma unroll
  for (int i=0;i<4;i++){
    int r = tc + i*8;
    xt[((size_t)(b*SPB + st*32 + r))*256 + ct*32 + ts] = f2b(t[ts][r]);
  }
}

// fused row/col parity-min over h = cat[...,0:256]
__global__ void minrc_k(const u16* __restrict__ cat, float* __restrict__ rmin, float* __restrict__ cmin){
  int b = blockIdx.x/56, j = blockIdx.x%56, c = threadIdx.x;
  float mE=3.4e38f, mO=3.4e38f;
  if (blockIdx.y == 0) {
    const u16* base = cat + ((size_t)(b*SPB + j*56))*512 + c;
    #pragma unroll 4
    for (int x=0;x<56;x+=2){
      mE = fminf(mE, b2f(base[(size_t)x*512]));
      mO = fminf(mO, b2f(base[(size_t)(x+1)*512]));
    }
    rmin[((size_t)(b*2+0)*56 + j)*256 + c]=mE;
    rmin[((size_t)(b*2+1)*56 + j)*256 + c]=mO;
  } else {
    const u16* base = cat + ((size_t)(b*SPB + j))*512 + c;
    #pragma unroll 4
    for (int y=0;y<56;y+=2){
      mE = fminf(mE, b2f(base[(size_t)(y*56)*512]));
      mO = fminf(mO, b2f(base[(size_t)((y+1)*56)*512]));
    }
    cmin[((size_t)(b*2+0)*56 + j)*256 + c]=mE;
    cmin[((size_t)(b*2+1)*56 + j)*256 + c]=mO;
  }
}

// xj = max(0, h - min(colMinP[y%2][x], rowMinP[x%2][y])) -> cat[...,256:512]
__global__ void xj_k(u16* __restrict__ cat, const float* __restrict__ rmin, const float* __restrict__ cmin){
  int b = blockIdx.y, s = blockIdx.x, c = threadIdx.x;
  int y = s/56, x = s%56;
  size_t idx = ((size_t)(b*SPB + s))*512;
  float h = b2f(cat[idx + c]);
  float m = fminf(cmin[((size_t)(b*2+(y&1))*56 + x)*256 + c],
                  rmin[((size_t)(b*2+(x&1))*56 + y)*256 + c]);
  cat[idx + 256 + c] = f2b(fmaxf(0.0f, h - m));
}

// GEMM: D[m][o] = sum_k Ain[m][k] * Wp(packed)[o][k].
// SINGLE-WAVE workgroups, 64m x 64n wave tile (4x4 MFMA), NO barriers anywhere.
// A frags loaded direct from global (16 rows x 64B full lines); B frags from the
// fragment-packed weight array (contiguous 1KB per frag, shared across co-resident
// waves with the same nb -> L1 broadcast). Depth-2 register double buffer; the
// compiler issues fine-grained vmcnt waits since no barrier forces a drain.
// EPI 1: bf16( acc*s + t )              -> out [m][512] at col o0
// EPI 2: bf16( gelu(acc*s + t) )        -> out [m][512] at col o0
// EPI 3: fp32( acc*s + t + x[b][o][s] ) -> out [b][256][s]
template<int KTOT, int EPI>
__global__ __launch_bounds__(64, 2) void gemm_k(
    const u16* __restrict__ Ain, const u16* __restrict__ Bp,
    const float* __restrict__ scale, const float* __restrict__ bias,
    void* __restrict__ outp, const float* __restrict__ resid)
{
  constexpr int NIT = KTOT/32;
  __shared__ __align__(16) u16 smem[EPI==3 ? 8704 : 4608]; // epilogue only (per-wave)
  const int lane = threadIdx.x;
  const int quad = lane >> 4, l16 = lane & 15;
  const int m0 = blockIdx.x * 64;
  const int nb = blockIdx.y, o0 = nb * 64;

  float4v acc[4][4];
  #pragma unroll
  for (int i=0;i<4;i++)
    #pragma unroll
    for (int j=0;j<4;j++) acc[i][j] = (float4v){0.f,0.f,0.f,0.f};

  const u16* aB = Ain + (size_t)(m0 + l16)*KTOT + quad*8;
  const u16* bB = Bp + (size_t)nb*NIT*2048 + lane*8;   // NIT*4*64*8 u16 per nb

  short8 afb[2][4], bfb[2][4];
  #pragma unroll
  for (int im=0;im<4;im++) afb[0][im] = *(const short8*)(aB + im*16*KTOT);
  #pragma unroll
  for (int in=0;in<4;in++) bfb[0][in] = *(const short8*)(bB + in*512);

  #pragma unroll
  for (int it=0; it<NIT; ++it){
    const int cur = it & 1, nxt = cur ^ 1;
    if (it + 1 < NIT){
      #pragma unroll
      for (int im=0;im<4;im++) afb[nxt][im] = *(const short8*)(aB + im*16*KTOT + (it+1)*32);
      #pragma unroll
      for (int in=0;in<4;in++) bfb[nxt][in] = *(const short8*)(bB + ((it+1)*4+in)*512);
    }
    #pragma unroll
    for (int im=0;im<4;im++)
      #pragma unroll
      for (int in=0;in<4;in++)
        acc[im][in] = __builtin_amdgcn_mfma_f32_16x16x32_bf16(afb[cur][im], bfb[cur][in], acc[im][in], 0, 0, 0);
  }

  if (EPI == 1 || EPI == 2) {
    u16* tile = smem; // [64 m][72 o] padded
    #pragma unroll
    for (int im=0;im<4;im++)
      #pragma unroll
      for (int in=0;in<4;in++){
        int ol = in*16 + l16;
        float sc = scale[o0+ol], bi = bias[o0+ol];
        #pragma unroll
        for (int r=0;r<4;r++){
          float v = acc[im][in][r]*sc + bi;
          if (EPI==2) v = gelu_f(v);
          tile[(im*16+quad*4+r)*72 + ol] = f2b(v);
        }
      }
    // same-wave ds ordering handled by compiler waitcnts; no barrier needed
    u16* op = (u16*)outp;
    #pragma unroll
    for (int p=0;p<8;p++){
      int rr = p*8 + (lane>>3), off = (lane&7)*8;
      *(uint4*)&op[((size_t)(m0 + rr))*512 + o0 + off] = *(const uint4*)&tile[rr*72 + off];
    }
  } else {
    float* ftile = (float*)smem; // [64 o][68 m] padded
    float* op = (float*)outp;
    const int b = m0 / SPB, s0 = m0 - b*SPB;
    #pragma unroll
    for (int im=0;im<4;im++)
      #pragma unroll
      for (int in=0;in<4;in++){
        int c64 = in*16 + l16;
        int og = o0 + c64;
        float sc = scale[og], bi = bias[og];
        float4v v;
        #pragma unroll
        for (int r=0;r<4;r++) v[r] = acc[im][in][r]*sc + bi;
        *(float4v*)&ftile[c64*68 + im*16 + quad*4] = v;
      }
    #pragma unroll
    for (int it=0; it<16; ++it){
      int c = it*4 + (lane>>4), soff = (lane&15)*4;
      size_t g = ((size_t)(b*256 + o0 + c))*SPB + s0 + soff;
      float4v v = *(const float4v*)&ftile[c*68 + soff];
      v.x += resid[g]; v.y += resid[g+1]; v.z += resid[g+2]; v.w += resid[g+3];
      *(float4v*)&op[g] = v;
    }
  }
}

extern "C" void kernel_launch(void* const* d_in, const int* in_sizes, int n_in,
                              void* d_out, int out_size, void* d_ws, size_t ws_size,
                              hipStream_t stream)
{
  const float* x  = (const float*)d_in[0];
  const float* w1 = (const float*)d_in[1];
  const float* b1 = (const float*)d_in[2];
  const float* g1 = (const float*)d_in[3];
  const float* be1= (const float*)d_in[4];
  const float* m1 = (const float*)d_in[5];
  const float* v1 = (const float*)d_in[6];
  const float* wg = (const float*)d_in[7];
  const float* bg = (const float*)d_in[8];
  const float* gg = (const float*)d_in[9];
  const float* beg= (const float*)d_in[10];
  const float* mg = (const float*)d_in[11];
  const float* vg = (const float*)d_in[12];
  const float* w2 = (const float*)d_in[13];
  const float* b2 = (const float*)d_in[14];
  const float* g2 = (const float*)d_in[15];
  const float* be2= (const float*)d_in[16];
  const float* m2 = (const float*)d_in[17];
  const float* v2 = (const float*)d_in[18];

  char* ws = (char*)d_ws;
  size_t off = 0;
  auto alloc = [&](size_t bytes){ void* p = ws + off; off += (bytes + 255) & ~(size_t)255; return p; };
  u16* xt    = (u16*)alloc((size_t)MTOT*256*2);   // x transposed, bf16
  u16* catt  = (u16*)alloc((size_t)MTOT*512*2);   // [h ; xj] transposed, bf16
  u16* gt    = (u16*)alloc((size_t)MTOT*512*2);   // gelu output transposed, bf16
  u16* w1p   = (u16*)alloc((size_t)65536*2);      // packed weights
  u16* wgp   = (u16*)alloc((size_t)262144*2);
  u16* w2p   = (u16*)alloc((size_t)131072*2);
  float* cst = (float*)alloc((size_t)2048*4);
  float* rmin= (float*)alloc((size_t)NB*2*56*256*4);
  float* cmin= (float*)alloc((size_t)NB*2*56*256*4);

  hipLaunchKernelGGL(prep_k, dim3(512), dim3(512), 0, stream,
                     b1,g1,be1,m1,v1, bg,gg,beg,mg,vg, b2,g2,be2,m2,v2,
                     w1,wg,w2, w1p,wgp,w2p, cst);
  hipLaunchKernelGGL(transpose_x_k, dim3(98,8,8), dim3(32,8), 0, stream, x, xt);
  hipLaunchKernelGGL((gemm_k<256,1>), dim3(392,4), dim3(64), 0, stream,
                     xt, w1p, cst+0, cst+256, (void*)catt, (const float*)nullptr);
  hipLaunchKernelGGL(minrc_k, dim3(NB*56,2), dim3(256), 0, stream, catt, rmin, cmin);
  hipLaunchKernelGGL(xj_k, dim3(SPB, NB), dim3(256), 0, stream, catt, rmin, cmin);
  hipLaunchKernelGGL((gemm_k<512,2>), dim3(392,8), dim3(64), 0, stream,
                     catt, wgp, cst+512, cst+1024, (void*)gt, (const float*)nullptr);
  hipLaunchKernelGGL((gemm_k<512,3>), dim3(392,4), dim3(64), 0, stream,
                     gt, w2p, cst+1536, cst+1792, d_out, x);
}

// Round 6
// 216.971 us; speedup vs baseline: 1.0390x; 1.0390x over previous
//
#include <hip/hip_runtime.h>
#include <math.h>

#define SPB 3136      // spatial positions per batch (56*56)
#define NB 8
#define MTOT (NB*SPB) // 25088 = 196*128, flattened M across batch
#define EPS 1e-5f

typedef unsigned short u16;
typedef __attribute__((ext_vector_type(8))) short short8;
typedef __attribute__((ext_vector_type(4))) float float4v;

__device__ __forceinline__ float b2f(u16 v){ unsigned u=((unsigned)v)<<16; float f; __builtin_memcpy(&f,&u,4); return f; }
__device__ __forceinline__ u16 f2b(float f){ unsigned u; __builtin_memcpy(&u,&f,4); u += 0x7fffu + ((u>>16)&1u); return (u16)(u>>16); }
__device__ __forceinline__ float gelu_f(float z){ return 0.5f*z*(1.0f+erff(z*0.70710678118654752f)); }

// async global->LDS, 16B per lane; lds dest is wave-uniform base + lane*16 by construction
__device__ __forceinline__ void gll16(const u16* g, u16* l){
  __builtin_amdgcn_global_load_lds((const __attribute__((address_space(1))) void*)g,
                                   (__attribute__((address_space(3))) void*)l, 16, 0, 0);
}

// ---- fused: fold BN constants (block 0) + cast all weights to bf16 (row-major [o][k]) ----
// cst layout: s1[256] t1[256] sg[512] tg[512] s2[256] t2[256]
__global__ void prep_k(const float* b1,const float* g1,const float* be1,const float* m1,const float* v1,
                       const float* bg,const float* gg,const float* beg,const float* mg,const float* vg,
                       const float* b2,const float* g2,const float* be2,const float* m2,const float* v2,
                       const float* __restrict__ w1,const float* __restrict__ wg,const float* __restrict__ w2,
                       u16* __restrict__ w1b,u16* __restrict__ wgb,u16* __restrict__ w2b,
                       float* cst){
  int i = blockIdx.x*512 + threadIdx.x;
  if (blockIdx.x == 0) {
    int t = threadIdx.x;
    if (t < 256) {
      float s = g1[t]*rsqrtf(v1[t]+EPS);
      cst[t] = s; cst[256+t] = b1[t]*s + be1[t] - m1[t]*s;
      float s2 = g2[t]*rsqrtf(v2[t]+EPS);
      cst[1536+t] = s2; cst[1792+t] = b2[t]*s2 + be2[t] - m2[t]*s2;
    }
    float s = gg[t]*rsqrtf(vg[t]+EPS);
    cst[512+t] = s; cst[1024+t] = bg[t]*s + beg[t] - mg[t]*s;
  }
  if (i < 65536)  w1b[i] = f2b(w1[i]);
  if (i < 131072) w2b[i] = f2b(w2[i]);
  if (i < 262144) wgb[i] = f2b(wg[i]);
}

// x [b][c][s] fp32 -> xt [b][s][c] bf16
__global__ void transpose_x_k(const float* __restrict__ x, u16* __restrict__ xt){
  __shared__ float t[32][33];
  int b = blockIdx.z, ct = blockIdx.y, st = blockIdx.x;
  int ts = threadIdx.x, tc = threadIdx.y;
  #pragma unroll
  for (int i=0;i<4;i++){
    int c = tc + i*8;
    t[c][ts] = x[((size_t)(b*256 + ct*32 + c))*SPB + st*32 + ts];
  }
  __syncthreads();
  #pragma unroll
  for (int i=0;i<4;i++){
    int r = tc + i*8;
    xt[((size_t)(b*SPB + st*32 + r))*256 + ct*32 + ts] = f2b(t[ts][r]);
  }
}

// fused row/col parity-min over h = cat[...,0:256]
__global__ void minrc_k(const u16* __restrict__ cat, float* __restrict__ rmin, float* __restrict__ cmin){
  int b = blockIdx.x/56, j = blockIdx.x%56, c = threadIdx.x;
  float mE=3.4e38f, mO=3.4e38f;
  if (blockIdx.y == 0) {
    const u16* base = cat + ((size_t)(b*SPB + j*56))*512 + c;
    #pragma unroll 4
    for (int x=0;x<56;x+=2){
      mE = fminf(mE, b2f(base[(size_t)x*512]));
      mO = fminf(mO, b2f(base[(size_t)(x+1)*512]));
    }
    rmin[((size_t)(b*2+0)*56 + j)*256 + c]=mE;
    rmin[((size_t)(b*2+1)*56 + j)*256 + c]=mO;
  } else {
    const u16* base = cat + ((size_t)(b*SPB + j))*512 + c;
    #pragma unroll 4
    for (int y=0;y<56;y+=2){
      mE = fminf(mE, b2f(base[(size_t)(y*56)*512]));
      mO = fminf(mO, b2f(base[(size_t)((y+1)*56)*512]));
    }
    cmin[((size_t)(b*2+0)*56 + j)*256 + c]=mE;
    cmin[((size_t)(b*2+1)*56 + j)*256 + c]=mO;
  }
}

// xj = max(0, h - min(colMinP[y%2][x], rowMinP[x%2][y])) -> cat[...,256:512]
__global__ void xj_k(u16* __restrict__ cat, const float* __restrict__ rmin, const float* __restrict__ cmin){
  int b = blockIdx.y, s = blockIdx.x, c = threadIdx.x;
  int y = s/56, x = s%56;
  size_t idx = ((size_t)(b*SPB + s))*512;
  float h = b2f(cat[idx + c]);
  float m = fminf(cmin[((size_t)(b*2+(y&1))*56 + x)*256 + c],
                  rmin[((size_t)(b*2+(x&1))*56 + y)*256 + c]);
  cat[idx + 256 + c] = f2b(fmaxf(0.0f, h - m));
}

// GEMM: D[m][o] = sum_k Ain[m][k] * Wt[o][k]; M flattened over batch.
// BM=128 x BN=128 x BK=64. 4 waves (2x2), wave tile 64x64, 32 MFMA per wave per
// barrier. Explicit LDS double buffer (2 x 32KB, fragment-contiguous layout):
// staging chunk c (16B) -> LDS offset c*16, which IS frag (c>>6), lane (c&63).
// Next iteration's 8 gll16/thread are issued at the TOP of the compute phase, so
// the vmcnt(0) drain at the barrier waits on loads aged a full compute phase.
// ds_read_b128 frag reads are conflict-free (lane-contiguous 16B).
// EPI 1: bf16( acc*s + t )              -> out [m][512] at col o0
// EPI 2: bf16( gelu(acc*s + t) )        -> out [m][512] at col o0
// EPI 3: fp32( acc*s + t + x[b][o][s] ) -> out [b][256][s]
template<int KTOT, int NBN, int EPI>
__global__ __launch_bounds__(256) void gemm_k(
    const u16* __restrict__ Ain, const u16* __restrict__ Wt,
    const float* __restrict__ scale, const float* __restrict__ bias,
    void* __restrict__ outp, const float* __restrict__ resid)
{
  __shared__ __align__(16) u16 smem[32768];   // 64 KB: two 32KB buffers / epilogue
  const int tid = threadIdx.x;
  const int gy = blockIdx.x & (NBN-1);        // consecutive blocks share the A m-tile
  const int mx = blockIdx.x / NBN;
  const int m0 = mx*128, o0 = gy*128;
  const int lane = tid & 63, wid = tid >> 6;
  const int quad = lane >> 4, l16 = lane & 15;
  const int wm = wid & 1, wn = wid >> 1;
  constexpr int NIT = KTOT/64;

  // staging address precompute: chunk c = s*256+tid; row=(c>>7)*16+(c&15),
  // k-offset = ((c>>6)&1)*32 + ((c>>4)&3)*8  (fragment-order inverse map)
  const u16* gA[4]; const u16* gB[4];
  #pragma unroll
  for (int s=0;s<4;s++){
    int c = s*256 + tid;
    int row = ((c>>7)<<4) + (c&15);
    int kof = ((c>>6)&1)*32 + ((c>>4)&3)*8;
    gA[s] = Ain + (size_t)(m0+row)*KTOT + kof;
    gB[s] = Wt  + (size_t)(o0+row)*KTOT + kof;
  }

  float4v acc[4][4];
  #pragma unroll
  for (int i=0;i<4;i++)
    #pragma unroll
    for (int j=0;j<4;j++) acc[i][j] = (float4v){0.f,0.f,0.f,0.f};

  // prologue: stage iter 0 into buffer 0
  {
    u16* dst = smem;
    #pragma unroll
    for (int s=0;s<4;s++){
      gll16(gA[s], dst + (s*256+tid)*8);
      gll16(gB[s], dst + 8192 + (s*256+tid)*8);
    }
  }
  __syncthreads();

  for (int it=0; it<NIT; ++it){
    if (it+1 < NIT){
      u16* dst = smem + ((it+1)&1)*16384;
      const int kt = (it+1)*64;
      #pragma unroll
      for (int s=0;s<4;s++){
        gll16(gA[s] + kt, dst + (s*256+tid)*8);
        gll16(gB[s] + kt, dst + 8192 + (s*256+tid)*8);
      }
    }
    const u16* buf = smem + (it&1)*16384;
    #pragma unroll
    for (int ki=0; ki<2; ++ki){
      short8 af[4], bf[4];
      #pragma unroll
      for (int mi=0;mi<4;mi++) af[mi] = *(const short8*)&buf[(((wm*4+mi)*2+ki)*64 + lane)*8];
      #pragma unroll
      for (int ni=0;ni<4;ni++) bf[ni] = *(const short8*)&buf[8192 + (((wn*4+ni)*2+ki)*64 + lane)*8];
      #pragma unroll
      for (int mi=0;mi<4;mi++)
        #pragma unroll
        for (int ni=0;ni<4;ni++)
          acc[mi][ni] = __builtin_amdgcn_mfma_f32_16x16x32_bf16(af[mi], bf[ni], acc[mi][ni], 0, 0, 0);
    }
    __syncthreads();
  }

  if (EPI == 1 || EPI == 2) {
    u16* tile = smem; // [128 m][128 o] = 32KB
    #pragma unroll
    for (int im=0;im<4;im++)
      #pragma unroll
      for (int in=0;in<4;in++){
        int ol = wn*64 + in*16 + l16;
        float sc = scale[o0+ol], bi = bias[o0+ol];
        #pragma unroll
        for (int r=0;r<4;r++){
          float v = acc[im][in][r]*sc + bi;
          if (EPI==2) v = gelu_f(v);
          tile[(wm*64+im*16+quad*4+r)*128 + ol] = f2b(v);
        }
      }
    __syncthreads();
    u16* op = (u16*)outp;
    #pragma unroll
    for (int p=0;p<8;p++){
      int chunk = p*256 + tid;
      int rr = chunk >> 4, off = (chunk & 15)*8;
      *(uint4*)&op[((size_t)(m0 + rr))*512 + o0 + off] = *(const uint4*)&tile[rr*128 + off];
    }
  } else {
    float* ftile = (float*)smem; // [64 o][132 m] padded = 33.8KB, one 64-chan half at a time
    float* op = (float*)outp;
    #pragma unroll
    for (int h=0; h<2; h++){
      if (wn == h){
        #pragma unroll
        for (int im=0;im<4;im++)
          #pragma unroll
          for (int in=0;in<4;in++){
            int c64 = in*16 + l16;
            int og = o0 + h*64 + c64;
            float sc = scale[og], bi = bias[og];
            float4v v;
            #pragma unroll
            for (int r=0;r<4;r++) v[r] = acc[im][in][r]*sc + bi;
            *(float4v*)&ftile[c64*132 + wm*64 + im*16 + quad*4] = v;
          }
      }
      __syncthreads();
      #pragma unroll
      for (int p=0;p<8;p++){
        int chunk = p*256 + tid;
        int rr = chunk >> 5, off = (chunk & 31)*4;
        int m = m0 + off;
        int b = m / SPB, s = m - b*SPB;
        size_t g = ((size_t)(b*256 + o0 + h*64 + rr))*SPB + s;
        float4v v = *(const float4v*)&ftile[rr*132 + off];
        v.x += resid[g]; v.y += resid[g+1]; v.z += resid[g+2]; v.w += resid[g+3];
        *(float4v*)&op[g] = v;
      }
      __syncthreads();
    }
  }
}

extern "C" void kernel_launch(void* const* d_in, const int* in_sizes, int n_in,
                              void* d_out, int out_size, void* d_ws, size_t ws_size,
                              hipStream_t stream)
{
  const float* x  = (const float*)d_in[0];
  const float* w1 = (const float*)d_in[1];
  const float* b1 = (const float*)d_in[2];
  const float* g1 = (const float*)d_in[3];
  const float* be1= (const float*)d_in[4];
  const float* m1 = (const float*)d_in[5];
  const float* v1 = (const float*)d_in[6];
  const float* wg = (const float*)d_in[7];
  const float* bg = (const float*)d_in[8];
  const float* gg = (const float*)d_in[9];
  const float* beg= (const float*)d_in[10];
  const float* mg = (const float*)d_in[11];
  const float* vg = (const float*)d_in[12];
  const float* w2 = (const float*)d_in[13];
  const float* b2 = (const float*)d_in[14];
  const float* g2 = (const float*)d_in[15];
  const float* be2= (const float*)d_in[16];
  const float* m2 = (const float*)d_in[17];
  const float* v2 = (const float*)d_in[18];

  char* ws = (char*)d_ws;
  size_t off = 0;
  auto alloc = [&](size_t bytes){ void* p = ws + off; off += (bytes + 255) & ~(size_t)255; return p; };
  u16* xt    = (u16*)alloc((size_t)MTOT*256*2);   // x transposed, bf16
  u16* catt  = (u16*)alloc((size_t)MTOT*512*2);   // [h ; xj] transposed, bf16
  u16* gt    = (u16*)alloc((size_t)MTOT*512*2);   // gelu output transposed, bf16
  u16* w1b   = (u16*)alloc((size_t)65536*2);
  u16* wgb   = (u16*)alloc((size_t)262144*2);
  u16* w2b   = (u16*)alloc((size_t)131072*2);
  float* cst = (float*)alloc((size_t)2048*4);
  float* rmin= (float*)alloc((size_t)NB*2*56*256*4);
  float* cmin= (float*)alloc((size_t)NB*2*56*256*4);

  hipLaunchKernelGGL(prep_k, dim3(512), dim3(512), 0, stream,
                     b1,g1,be1,m1,v1, bg,gg,beg,mg,vg, b2,g2,be2,m2,v2,
                     w1,wg,w2, w1b,wgb,w2b, cst);
  hipLaunchKernelGGL(transpose_x_k, dim3(98,8,8), dim3(32,8), 0, stream, x, xt);
  hipLaunchKernelGGL((gemm_k<256,2,1>), dim3(196*2), dim3(256), 0, stream,
                     xt, w1b, cst+0, cst+256, (void*)catt, (const float*)nullptr);
  hipLaunchKernelGGL(minrc_k, dim3(NB*56,2), dim3(256), 0, stream, catt, rmin, cmin);
  hipLaunchKernelGGL(xj_k, dim3(SPB, NB), dim3(256), 0, stream, catt, rmin, cmin);
  hipLaunchKernelGGL((gemm_k<512,4,2>), dim3(196*4), dim3(256), 0, stream,
                     catt, wgb, cst+512, cst+1024, (void*)gt, (const float*)nullptr);
  hipLaunchKernelGGL((gemm_k<512,2,3>), dim3(196*2), dim3(256), 0, stream,
                     gt, w2b, cst+1536, cst+1792, d_out, x);
}